// Round 9
// baseline (298.667 us; speedup 1.0000x reference)
//
#include <hip/hip_runtime.h>
#include <cstdint>

// Exact radix-select on order-transformed x bits among t<0 entries
// (t = -1 exactly => negative_loss = softplus(x), strictly increasing in x).
// R9: 5 dispatches total (memset, k1, scanA, k2, final).
//  - k1: wave-level compaction (R8) + global 2^21-bin hist (bits [31:11]) via
//    fire-and-forget atomics. No LDS, no barriers.
//  - scanA: 1024 blocks -> per-2048-bin-chunk sums of hist21.
//  - k2: per-block PROLOGUE redundantly selects the 21-bit prefix from
//    csums+hist21 (L2-hot), then streams the compact array building a global
//    2048-bin hist of the low 11 bits.
//  - final: prologue redoes the selection incl. low bits -> u_kth, thr; then
//    streams x,t writing the loss. Fast __expf/__logf values, exact
//    bit-compare mask, precise log1pf re-check within a 256-ulp guard band.
//
// ws layout:
//   [0    ..  4096)  csums (1024 u32)
//   [4096 .. 12288)  hist2 (2048 u32)  low 11 bits
//   [12288.. 20480)  bcount (2048 u32) per-block segment cursors
//   [32768.. 32768+8MB)  hist21 (2^21 u32)  bits [31:11]
//   [.. )            compact segments (cap u32 per block)

#define GUARD 256u

__device__ __forceinline__ uint32_t xform(uint32_t b) {
    return ((int32_t)b < 0) ? ~b : (b | 0x80000000u);
}
__device__ __forceinline__ float unxform(uint32_t u) {
    uint32_t b = (u & 0x80000000u) ? (u ^ 0x80000000u) : ~u;
    return __uint_as_float(b);
}
// precise chain — matches reference fp32 semantics (threshold + guard band)
__device__ __forceinline__ float neg_loss_precise(float xx, float tt) {
#pragma clang fp contract(off)
    return (fmaxf(-xx, 0.0f) - xx * tt) + log1pf(expf(-fabsf(xx)));
}

// ---------------- k1: wave compaction + global hist21 (no LDS/barriers) ----
__global__ __launch_bounds__(256) void k1_compact(
        const float* __restrict__ x, const float* __restrict__ t,
        uint32_t* __restrict__ comp, uint32_t* __restrict__ bcount,
        uint32_t* __restrict__ h21, uint32_t cap, int n) {
    const int n4 = n >> 2;
    const int S = gridDim.x * 256;
    uint32_t* __restrict__ seg = comp ? comp + (size_t)blockIdx.x * cap : nullptr;
    uint32_t* __restrict__ cur = &bcount[blockIdx.x];
    const float4* __restrict__ x4 = (const float4*)x;
    const float4* __restrict__ t4 = (const float4*)t;
    const int lane = threadIdx.x & 63;

    for (int ib = blockIdx.x * 256; ib < n4; ib += 2 * S) {   // block-uniform trips
        const int i1 = ib + threadIdx.x;
        const int i2 = i1 + S;
        const bool v1 = i1 < n4, v2 = i2 < n4;
        float4 xa, ta, xb, tb;
        if (v1) { xa = x4[i1]; ta = t4[i1]; }
        if (v2) { xb = x4[i2]; tb = t4[i2]; }
        uint32_t loc[8];
        int c = 0;
        if (v1) {
            uint32_t u;
            u = (ta.x < 0.0f) ? xform(__float_as_uint(xa.x)) : 0u; if (u) loc[c++] = u;
            u = (ta.y < 0.0f) ? xform(__float_as_uint(xa.y)) : 0u; if (u) loc[c++] = u;
            u = (ta.z < 0.0f) ? xform(__float_as_uint(xa.z)) : 0u; if (u) loc[c++] = u;
            u = (ta.w < 0.0f) ? xform(__float_as_uint(xa.w)) : 0u; if (u) loc[c++] = u;
        }
        if (v2) {
            uint32_t u;
            u = (tb.x < 0.0f) ? xform(__float_as_uint(xb.x)) : 0u; if (u) loc[c++] = u;
            u = (tb.y < 0.0f) ? xform(__float_as_uint(xb.y)) : 0u; if (u) loc[c++] = u;
            u = (tb.z < 0.0f) ? xform(__float_as_uint(xb.z)) : 0u; if (u) loc[c++] = u;
            u = (tb.w < 0.0f) ? xform(__float_as_uint(xb.w)) : 0u; if (u) loc[c++] = u;
        }
        // global histogram: fire-and-forget (no return -> no wait)
        for (int j = 0; j < c; ++j) atomicAdd(&h21[loc[j] >> 11], 1u);
        // wave compaction: shfl prefix over per-lane counts, 1 atomic/wave
        if (seg && __ballot(c > 0)) {
            int pfx = c;
#pragma unroll
            for (int off = 1; off < 64; off <<= 1) {
                int vv = __shfl_up(pfx, off);
                if (lane >= off) pfx += vv;
            }
            const int tot = __shfl(pfx, 63);
            uint32_t base = 0;
            if (lane == 63) base = atomicAdd(cur, (uint32_t)tot);
            base = __shfl(base, 63);
            uint32_t o = base + (uint32_t)(pfx - c);
            for (int j = 0; j < c; ++j) seg[o + j] = loc[j];
        }
    }
    if (blockIdx.x == 0) {                   // n % 4 tail (<= 3 elems)
        const int j = (n4 << 2) + threadIdx.x;
        uint32_t u = 0;
        if (j < n && t[j] < 0.0f) u = xform(__float_as_uint(x[j]));
        if (u) atomicAdd(&h21[u >> 11], 1u);
        const int c = u ? 1 : 0;
        if (seg && __ballot(c > 0)) {
            int pfx = c;
#pragma unroll
            for (int off = 1; off < 64; off <<= 1) {
                int vv = __shfl_up(pfx, off);
                if (lane >= off) pfx += vv;
            }
            const int tot = __shfl(pfx, 63);
            uint32_t base = 0;
            if (lane == 63) base = atomicAdd(cur, (uint32_t)tot);
            base = __shfl(base, 63);
            if (c) seg[base + (uint32_t)(pfx - 1)] = u;
        }
    }
}

// ---------------- scanA: per-chunk sums of hist21 (1024 x 2048) ------------
__global__ __launch_bounds__(256) void scanA(
        const uint32_t* __restrict__ h21, uint32_t* __restrict__ csums) {
    __shared__ uint32_t red[256];
    const uint4* b4 = (const uint4*)(h21 + (size_t)blockIdx.x * 2048);
    uint32_t s = 0;
    for (int j = threadIdx.x; j < 512; j += 256) {
        uint4 v = b4[j];
        s += v.x + v.y + v.z + v.w;
    }
    red[threadIdx.x] = s;
    __syncthreads();
    for (int off = 128; off > 0; off >>= 1) {
        if (threadIdx.x < off) red[threadIdx.x] += red[threadIdx.x + off];
        __syncthreads();
    }
    if (threadIdx.x == 0) csums[blockIdx.x] = red[0];
}

// ---------------- block-local k-th-largest pick over nbins = 256*CH --------
// part = 256-entry LDS scratch; sel = {bin, krem, total} LDS.
// Writers to sel[0..1] exist iff 1 <= k <= total.
template<int CH>
__device__ void pick_kth(const uint32_t* __restrict__ h, uint32_t k,
                         uint32_t* part, uint32_t* sel) {
    const int tid = threadIdx.x;
    uint32_t cnt[CH];
    uint32_t lsum = 0;
#pragma unroll
    for (int j = 0; j < CH; ++j) { cnt[j] = h[tid * CH + j]; lsum += cnt[j]; }
    part[tid] = lsum;
    __syncthreads();
    for (int off = 1; off < 256; off <<= 1) {  // inclusive suffix sum
        uint32_t add = (tid + off < 256) ? part[tid + off] : 0u;
        __syncthreads();
        part[tid] += add;
        __syncthreads();
    }
    if (tid == 0) sel[2] = part[0];
    uint32_t A = (tid < 255) ? part[tid + 1] : 0u;  // strictly-above count
#pragma unroll
    for (int j = CH - 1; j >= 0; --j) {
        uint32_t c = cnt[j];
        if (A < k && k <= A + c) { sel[0] = (uint32_t)(tid * CH + j); sel[1] = k - A; }
        A += c;
    }
    __syncthreads();
}

// Redundant per-block selection prologue. mode 1: stop after 21-bit prefix
// (k2). mode 2: full -> u_kth, thr (final). Returns 0 normal, 1 keep-all,
// 2 drop-all (uniform across the block).
__device__ int sel_prologue(const uint32_t* __restrict__ h21,
                            const uint32_t* __restrict__ csums,
                            const uint32_t* __restrict__ hist2,
                            const int* __restrict__ kptr, int mode,
                            uint32_t* part, uint32_t* sel,
                            uint32_t* p21_out, uint32_t* ukth, float* thr) {
    int kk = *kptr;
    if (kk <= 0) { *ukth = 0xFFFFFFFFu; *thr = __int_as_float(0x7F800000); return 1; }
    const uint32_t k = (uint32_t)kk;
    pick_kth<4>(csums, k, part, sel);            // level A: 1024 chunks
    if (k > sel[2]) { *ukth = 0u; *thr = 0.0f; return 2; }
    const uint32_t chunk = sel[0];
    const uint32_t kA = sel[1];
    __syncthreads();
    pick_kth<8>(h21 + (size_t)chunk * 2048u, kA, part, sel);  // level B: 2048 bins
    const uint32_t p21 = chunk * 2048u + sel[0];
    const uint32_t kB = sel[1];
    *p21_out = p21;
    if (mode == 1) return 0;
    __syncthreads();
    pick_kth<8>(hist2, kB, part, sel);           // level C: 2048 low bins
    const uint32_t u = (p21 << 11) | sel[0];
    *ukth = u;
    *thr = neg_loss_precise(unxform(u), -1.0f);  // t = -1 exactly
    return 0;
}

// ---------------- k2: low-11-bit hist of prefix-matching elems -------------
__global__ __launch_bounds__(256) void k2_low(
        const uint32_t* __restrict__ comp, const uint32_t* __restrict__ bcount,
        uint32_t cap, const uint32_t* __restrict__ h21,
        const uint32_t* __restrict__ csums, uint32_t* __restrict__ hist2,
        const int* __restrict__ kptr,
        const float* __restrict__ x, const float* __restrict__ t, int n) {
    __shared__ uint32_t part[256];
    __shared__ uint32_t sel[3];
    uint32_t p21 = 0, ukth; float thr;
    if (sel_prologue(h21, csums, nullptr, kptr, 1, part, sel, &p21, &ukth, &thr))
        return;  // uniform early exit; hist2 unused on this path

    if (comp) {
        const uint32_t cnt = bcount[blockIdx.x];
        const uint32_t* __restrict__ seg = comp + (size_t)blockIdx.x * cap;
        uint32_t j = threadIdx.x;
        for (; j + 768u < cnt; j += 1024u) {   // 4 loads in flight
            uint32_t a = seg[j], b = seg[j + 256], c = seg[j + 512], d = seg[j + 768];
            if ((a >> 11) == p21) atomicAdd(&hist2[a & 0x7FFu], 1u);
            if ((b >> 11) == p21) atomicAdd(&hist2[b & 0x7FFu], 1u);
            if ((c >> 11) == p21) atomicAdd(&hist2[c & 0x7FFu], 1u);
            if ((d >> 11) == p21) atomicAdd(&hist2[d & 0x7FFu], 1u);
        }
        for (; j < cnt; j += 256u) {
            uint32_t a = seg[j];
            if ((a >> 11) == p21) atomicAdd(&hist2[a & 0x7FFu], 1u);
        }
    } else {  // fallback: re-read x,t
        const float4* x4 = (const float4*)x;
        const float4* t4 = (const float4*)t;
        const int n4 = n >> 2;
        const int S = gridDim.x * 256;
        for (int i = blockIdx.x * 256 + threadIdx.x; i < n4; i += S) {
            float4 xv = x4[i], tv = t4[i];
            uint32_t u;
            u = (tv.x < 0.0f) ? xform(__float_as_uint(xv.x)) : 0u;
            if (u && (u >> 11) == p21) atomicAdd(&hist2[u & 0x7FFu], 1u);
            u = (tv.y < 0.0f) ? xform(__float_as_uint(xv.y)) : 0u;
            if (u && (u >> 11) == p21) atomicAdd(&hist2[u & 0x7FFu], 1u);
            u = (tv.z < 0.0f) ? xform(__float_as_uint(xv.z)) : 0u;
            if (u && (u >> 11) == p21) atomicAdd(&hist2[u & 0x7FFu], 1u);
            u = (tv.w < 0.0f) ? xform(__float_as_uint(xv.w)) : 0u;
            if (u && (u >> 11) == p21) atomicAdd(&hist2[u & 0x7FFu], 1u);
        }
        if (blockIdx.x == 0) {
            for (int j = (n4 << 2) + threadIdx.x; j < n; j += 256) {
                uint32_t u = (t[j] < 0.0f) ? xform(__float_as_uint(x[j])) : 0u;
                if (u && (u >> 11) == p21) atomicAdd(&hist2[u & 0x7FFu], 1u);
            }
        }
    }
}

// ---------------- final: fast-math values, bit-exact mask ------------------
__device__ __forceinline__ float fin1(float xx, float tt, uint32_t ukth, float thr) {
    float lp = __logf(1.0f + __expf(-fabsf(xx)));   // HW exp/log
    float v = 0.0f;
    if (tt > 0.0f) {
        v = fmaxf(xx, 0.0f) - xx * tt + lp;
    } else if (tt < 0.0f) {
        uint32_t u = xform(__float_as_uint(xx));
        bool keep = u < ukth;
        if (keep && (ukth - u) < GUARD)             // ~0 lanes hit this
            keep = neg_loss_precise(xx, tt) < thr;
        if (keep) v = fmaxf(-xx, 0.0f) - xx * tt + lp;
    }
    return v;
}

__device__ __forceinline__ float4 fin_quad(float4 xv, float4 tv, uint32_t ukth, float thr) {
    float4 r;
    r.x = fin1(xv.x, tv.x, ukth, thr);
    r.y = fin1(xv.y, tv.y, ukth, thr);
    r.z = fin1(xv.z, tv.z, ukth, thr);
    r.w = fin1(xv.w, tv.w, ukth, thr);
    return r;
}

__global__ __launch_bounds__(256) void k_final(
        const float* __restrict__ x, const float* __restrict__ t,
        const uint32_t* __restrict__ h21, const uint32_t* __restrict__ csums,
        const uint32_t* __restrict__ hist2, const int* __restrict__ kptr,
        float* __restrict__ out, int n) {
    __shared__ uint32_t part[256];
    __shared__ uint32_t sel[3];
    uint32_t p21, ukth = 0; float thr = 0.0f;
    sel_prologue(h21, csums, hist2, kptr, 2, part, sel, &p21, &ukth, &thr);
    // (e==1/2 set ukth/thr to keep-all / drop-all; e==0 full selection)

    const float4* x4 = (const float4*)x;
    const float4* t4 = (const float4*)t;
    float4* o4 = (float4*)out;
    const int n4 = n >> 2;
    const int S = gridDim.x * 256;
    int i = blockIdx.x * 256 + threadIdx.x;
    for (; i + 3 * S < n4; i += 4 * S) {
        float4 xa = x4[i], xb = x4[i + S], xc = x4[i + 2 * S], xd = x4[i + 3 * S];
        float4 ta = t4[i], tb = t4[i + S], tc = t4[i + 2 * S], td = t4[i + 3 * S];
        o4[i]         = fin_quad(xa, ta, ukth, thr);
        o4[i + S]     = fin_quad(xb, tb, ukth, thr);
        o4[i + 2 * S] = fin_quad(xc, tc, ukth, thr);
        o4[i + 3 * S] = fin_quad(xd, td, ukth, thr);
    }
    for (; i < n4; i += S) {
        float4 xa = x4[i], ta = t4[i];
        o4[i] = fin_quad(xa, ta, ukth, thr);
    }
    if (blockIdx.x == 0) {
        for (int j = (n4 << 2) + threadIdx.x; j < n; j += 256) {
            out[j] = fin1(x[j], t[j], ukth, thr);
        }
    }
}

extern "C" void kernel_launch(void* const* d_in, const int* in_sizes, int n_in,
                              void* d_out, int out_size, void* d_ws, size_t ws_size,
                              hipStream_t stream) {
    const float* x = (const float*)d_in[0];
    const float* t = (const float*)d_in[1];
    const int* kptr = (const int*)d_in[2];
    float* out = (float*)d_out;
    const int n = in_sizes[0];
    if (n <= 0) return;

    char* ws = (char*)d_ws;
    uint32_t* csums = (uint32_t*)(ws + 0);        // 1024 u32
    uint32_t* hist2 = (uint32_t*)(ws + 4096);     // 2048 u32
    uint32_t* bcnt  = (uint32_t*)(ws + 12288);    // 2048 u32
    uint32_t* h21   = (uint32_t*)(ws + 32768);    // 2^21 u32 (8 MB)
    const size_t h21_end = 32768 + (size_t)(1u << 21) * 4u;

    const int n4 = n >> 2;
    int work = (n4 + 255) / 256;
    if (work < 1) work = 1;
    const int grid1 = work < 2048 ? work : 2048;   // k1/k2 (per-segment)
    const int gridF = work < 2048 ? work : 2048;

    const int S = grid1 * 256;
    const uint32_t iters = (uint32_t)((n4 + 2 * S - 1) / (2 * S));
    const uint32_t cap = iters * 2048u + 8u;       // worst case: all negative
    const size_t need = h21_end + (size_t)cap * 4u * (size_t)grid1;
    uint32_t* comp = (ws_size >= need) ? (uint32_t*)(ws + h21_end) : nullptr;

    // zero csums/hist2/bcount + hist21 (~8.4 MB, one call)
    hipMemsetAsync(d_ws, 0, h21_end, stream);

    k1_compact<<<grid1, 256, 0, stream>>>(x, t, comp, bcnt, h21, cap, n);
    scanA     <<<1024, 256, 0, stream>>>(h21, csums);
    k2_low    <<<grid1, 256, 0, stream>>>(comp, bcnt, cap, h21, csums, hist2, kptr, x, t, n);
    k_final   <<<gridF, 256, 0, stream>>>(x, t, h21, csums, hist2, kptr, out, n);
}

// Round 10
// 189.842 us; speedup vs baseline: 1.5732x; 1.5732x over previous
//
#include <hip/hip_runtime.h>
#include <cstdint>

// Exact radix-select on order-transformed x bits among t<0 entries
// (t = -1 exactly => negative_loss = softplus(x), strictly increasing in x).
// R10: 5 dispatches (memset, k1, k2, scanA, final); no SelState, no 1-block
// scan kernels — selection is re-derived deterministically per block from
// L2-hot histograms.
//  - k1: 2048-bin LDS hist (bits [31:21]) + wave-batched compaction of all
//    negatives' u-bits into per-block segments (~13.6 MB). No global atomics.
//  - k2: per-block prologue picks the 11-bit prefix from hist1; streams the
//    compact segments scattering ONLY prefix-matching elems (~200k atomics)
//    into the 2^21-bin global hist (low 21 bits).
//  - scanA: 1024 blocks -> per-2048-bin-chunk sums of hist21.
//  - final: prologue re-derives p11 -> chunk -> bin => u_kth, thr; streams
//    x,t writing the loss. Fast __expf/__logf values, exact bit-compare
//    mask, precise log1pf re-check within a 256-ulp guard band.
//
// ws layout:
//   [0     ..  8192)  hist1 (2048 u32)   bits [31:21]
//   [8192  .. 12288)  csums (1024 u32)   chunk sums of h21
//   [16384 .. 24576)  bcount (2048 u32)  per-block segment cursors
//   [32768 .. 32768+8MB)  h21 (2^21 u32) bits [20:0] of matching elems
//   [.. )             compact segments (cap u32 per block)

#define GUARD 256u

__device__ __forceinline__ uint32_t xform(uint32_t b) {
    return ((int32_t)b < 0) ? ~b : (b | 0x80000000u);
}
__device__ __forceinline__ float unxform(uint32_t u) {
    uint32_t b = (u & 0x80000000u) ? (u ^ 0x80000000u) : ~u;
    return __uint_as_float(b);
}
// precise chain — matches reference fp32 semantics (threshold + guard band)
__device__ __forceinline__ float neg_loss_precise(float xx, float tt) {
#pragma clang fp contract(off)
    return (fmaxf(-xx, 0.0f) - xx * tt) + log1pf(expf(-fabsf(xx)));
}

__device__ __forceinline__ int pack4(float4 xv, float4 tv, uint32_t* loc, int c) {
    uint32_t u;
    u = (tv.x < 0.0f) ? xform(__float_as_uint(xv.x)) : 0u; if (u) loc[c++] = u;
    u = (tv.y < 0.0f) ? xform(__float_as_uint(xv.y)) : 0u; if (u) loc[c++] = u;
    u = (tv.z < 0.0f) ? xform(__float_as_uint(xv.z)) : 0u; if (u) loc[c++] = u;
    u = (tv.w < 0.0f) ? xform(__float_as_uint(xv.w)) : 0u; if (u) loc[c++] = u;
    return c;
}

// ---------------- k1: LDS hist (11 bits) + wave-batched compaction ---------
__global__ __launch_bounds__(256) void k1_hist_compact(
        const float* __restrict__ x, const float* __restrict__ t,
        uint32_t* __restrict__ comp, uint32_t* __restrict__ bcount,
        uint32_t* __restrict__ hist1, uint32_t cap, int n) {
    __shared__ uint32_t lh[2 * 2049];   // 2-way replicated (+1 pad)
    for (int i = threadIdx.x; i < 2 * 2049; i += 256) lh[i] = 0;
    __syncthreads();
    uint32_t* my = &lh[(threadIdx.x & 1) * 2049];
    uint32_t* __restrict__ seg = comp ? comp + (size_t)blockIdx.x * cap : nullptr;
    uint32_t* __restrict__ cur = &bcount[blockIdx.x];
    const float4* __restrict__ x4 = (const float4*)x;
    const float4* __restrict__ t4 = (const float4*)t;
    const int n4 = n >> 2;
    const int S = gridDim.x * 256;
    const int lane = threadIdx.x & 63;

    for (int ib = blockIdx.x * 256; ib < n4; ib += 4 * S) {   // block-uniform trips
        const int i1 = ib + threadIdx.x;
        const int i2 = i1 + S, i3 = i1 + 2 * S, i4 = i1 + 3 * S;
        const bool v1 = i1 < n4, v2 = i2 < n4, v3 = i3 < n4, v4 = i4 < n4;
        float4 xa, ta, xb, tb, xc, tc, xd, td;
        if (v1) { xa = x4[i1]; ta = t4[i1]; }
        if (v2) { xb = x4[i2]; tb = t4[i2]; }
        if (v3) { xc = x4[i3]; tc = t4[i3]; }
        if (v4) { xd = x4[i4]; td = t4[i4]; }
        uint32_t loc[16];
        int c = 0;
        if (v1) c = pack4(xa, ta, loc, c);
        if (v2) c = pack4(xb, tb, loc, c);
        if (v3) c = pack4(xc, tc, loc, c);
        if (v4) c = pack4(xd, td, loc, c);
        // LDS histogram of high 11 bits
        for (int j = 0; j < c; ++j) atomicAdd(&my[loc[j] >> 21], 1u);
        // wave compaction: one shfl-prefix + one global atomic per 16 elems
        if (seg && __ballot(c > 0)) {
            int pfx = c;
#pragma unroll
            for (int off = 1; off < 64; off <<= 1) {
                int vv = __shfl_up(pfx, off);
                if (lane >= off) pfx += vv;
            }
            const int tot = __shfl(pfx, 63);
            uint32_t base = 0;
            if (lane == 63) base = atomicAdd(cur, (uint32_t)tot);
            base = __shfl(base, 63);
            uint32_t o = base + (uint32_t)(pfx - c);
            for (int j = 0; j < c; ++j) seg[o + j] = loc[j];
        }
    }
    if (blockIdx.x == 0) {                   // n % 4 tail (<= 3 elems)
        const int j = (n4 << 2) + threadIdx.x;
        uint32_t u = 0;
        if (j < n && t[j] < 0.0f) u = xform(__float_as_uint(x[j]));
        if (u) atomicAdd(&my[u >> 21], 1u);
        const int c = u ? 1 : 0;
        if (seg && __ballot(c > 0)) {
            int pfx = c;
#pragma unroll
            for (int off = 1; off < 64; off <<= 1) {
                int vv = __shfl_up(pfx, off);
                if (lane >= off) pfx += vv;
            }
            const int tot = __shfl(pfx, 63);
            uint32_t base = 0;
            if (lane == 63) base = atomicAdd(cur, (uint32_t)tot);
            base = __shfl(base, 63);
            if (c) seg[base + (uint32_t)(pfx - 1)] = u;
        }
    }
    __syncthreads();
    for (int b = threadIdx.x; b < 2048; b += 256) {
        uint32_t cc = lh[b] + lh[2049 + b];
        if (cc) atomicAdd(&hist1[b], cc);
    }
}

// ---------------- block-local k-th-largest pick over nbins = 256*CH --------
// part = 256-entry LDS scratch; sel = {bin, krem, total}.
// Writers to sel[0..1] exist iff 1 <= k <= total. Ends with __syncthreads.
template<int CH>
__device__ void pick_kth(const uint32_t* __restrict__ h, uint32_t k,
                         uint32_t* part, uint32_t* sel) {
    const int tid = threadIdx.x;
    uint32_t cnt[CH];
    uint32_t lsum = 0;
#pragma unroll
    for (int j = 0; j < CH; ++j) { cnt[j] = h[tid * CH + j]; lsum += cnt[j]; }
    part[tid] = lsum;
    __syncthreads();
    for (int off = 1; off < 256; off <<= 1) {  // inclusive suffix sum
        uint32_t add = (tid + off < 256) ? part[tid + off] : 0u;
        __syncthreads();
        part[tid] += add;
        __syncthreads();
    }
    if (tid == 0) sel[2] = part[0];
    uint32_t A = (tid < 255) ? part[tid + 1] : 0u;  // strictly-above count
#pragma unroll
    for (int j = CH - 1; j >= 0; --j) {
        uint32_t c = cnt[j];
        if (A < k && k <= A + c) { sel[0] = (uint32_t)(tid * CH + j); sel[1] = k - A; }
        A += c;
    }
    __syncthreads();
}

// ---------------- k2: scatter matching elems' low 21 bits into h21 --------
__global__ __launch_bounds__(256) void k2_hist21(
        const uint32_t* __restrict__ comp, const uint32_t* __restrict__ bcount,
        uint32_t cap, const uint32_t* __restrict__ hist1,
        uint32_t* __restrict__ h21, const int* __restrict__ kptr,
        const float* __restrict__ x, const float* __restrict__ t, int n) {
    __shared__ uint32_t part[256];
    __shared__ uint32_t sel[3];
    const int kk = *kptr;
    if (kk <= 0) return;                      // keep-all: h21 unused
    pick_kth<8>(hist1, (uint32_t)kk, part, sel);
    if ((uint32_t)kk > sel[2]) return;        // drop-all: h21 unused
    const uint32_t p11 = sel[0];

    if (comp) {
        const uint32_t cnt = bcount[blockIdx.x];
        const uint32_t* __restrict__ seg = comp + (size_t)blockIdx.x * cap;
        uint32_t j = threadIdx.x;
        for (; j + 768u < cnt; j += 1024u) {   // 4 loads in flight
            uint32_t a = seg[j], b = seg[j + 256], c = seg[j + 512], d = seg[j + 768];
            if ((a >> 21) == p11) atomicAdd(&h21[a & 0x1FFFFFu], 1u);
            if ((b >> 21) == p11) atomicAdd(&h21[b & 0x1FFFFFu], 1u);
            if ((c >> 21) == p11) atomicAdd(&h21[c & 0x1FFFFFu], 1u);
            if ((d >> 21) == p11) atomicAdd(&h21[d & 0x1FFFFFu], 1u);
        }
        for (; j < cnt; j += 256u) {
            uint32_t a = seg[j];
            if ((a >> 21) == p11) atomicAdd(&h21[a & 0x1FFFFFu], 1u);
        }
    } else {  // fallback: re-read x,t (R5-proven)
        const float4* x4 = (const float4*)x;
        const float4* t4 = (const float4*)t;
        const int n4 = n >> 2;
        const int S = gridDim.x * 256;
        for (int i = blockIdx.x * 256 + threadIdx.x; i < n4; i += S) {
            float4 xv = x4[i], tv = t4[i];
            uint32_t u;
            u = (tv.x < 0.0f) ? xform(__float_as_uint(xv.x)) : 0u;
            if (u && (u >> 21) == p11) atomicAdd(&h21[u & 0x1FFFFFu], 1u);
            u = (tv.y < 0.0f) ? xform(__float_as_uint(xv.y)) : 0u;
            if (u && (u >> 21) == p11) atomicAdd(&h21[u & 0x1FFFFFu], 1u);
            u = (tv.z < 0.0f) ? xform(__float_as_uint(xv.z)) : 0u;
            if (u && (u >> 21) == p11) atomicAdd(&h21[u & 0x1FFFFFu], 1u);
            u = (tv.w < 0.0f) ? xform(__float_as_uint(xv.w)) : 0u;
            if (u && (u >> 21) == p11) atomicAdd(&h21[u & 0x1FFFFFu], 1u);
        }
        if (blockIdx.x == 0) {
            for (int j = (n4 << 2) + threadIdx.x; j < n; j += 256) {
                uint32_t u = (t[j] < 0.0f) ? xform(__float_as_uint(x[j])) : 0u;
                if (u && (u >> 21) == p11) atomicAdd(&h21[u & 0x1FFFFFu], 1u);
            }
        }
    }
}

// ---------------- scanA: per-chunk sums of h21 (1024 x 2048) ---------------
__global__ __launch_bounds__(256) void scanA(
        const uint32_t* __restrict__ h21, uint32_t* __restrict__ csums) {
    __shared__ uint32_t red[256];
    const uint4* b4 = (const uint4*)(h21 + (size_t)blockIdx.x * 2048);
    uint32_t s = 0;
    for (int j = threadIdx.x; j < 512; j += 256) {
        uint4 v = b4[j];
        s += v.x + v.y + v.z + v.w;
    }
    red[threadIdx.x] = s;
    __syncthreads();
    for (int off = 128; off > 0; off >>= 1) {
        if (threadIdx.x < off) red[threadIdx.x] += red[threadIdx.x + off];
        __syncthreads();
    }
    if (threadIdx.x == 0) csums[blockIdx.x] = red[0];
}

// ---------------- final: re-derive u_kth, then stream the loss -------------
__device__ __forceinline__ float fin1(float xx, float tt, uint32_t ukth, float thr) {
    float lp = __logf(1.0f + __expf(-fabsf(xx)));   // HW exp/log
    float v = 0.0f;
    if (tt > 0.0f) {
        v = fmaxf(xx, 0.0f) - xx * tt + lp;
    } else if (tt < 0.0f) {
        uint32_t u = xform(__float_as_uint(xx));
        bool keep = u < ukth;
        if (keep && (ukth - u) < GUARD)             // ~0 lanes hit this
            keep = neg_loss_precise(xx, tt) < thr;
        if (keep) v = fmaxf(-xx, 0.0f) - xx * tt + lp;
    }
    return v;
}

__device__ __forceinline__ float4 fin_quad(float4 xv, float4 tv, uint32_t ukth, float thr) {
    float4 r;
    r.x = fin1(xv.x, tv.x, ukth, thr);
    r.y = fin1(xv.y, tv.y, ukth, thr);
    r.z = fin1(xv.z, tv.z, ukth, thr);
    r.w = fin1(xv.w, tv.w, ukth, thr);
    return r;
}

__global__ __launch_bounds__(256) void k_final(
        const float* __restrict__ x, const float* __restrict__ t,
        const uint32_t* __restrict__ hist1, const uint32_t* __restrict__ csums,
        const uint32_t* __restrict__ h21, const int* __restrict__ kptr,
        float* __restrict__ out, int n) {
    __shared__ uint32_t part[256];
    __shared__ uint32_t sel[3];
    uint32_t ukth; float thr;
    const int kk = *kptr;
    if (kk <= 0) {
        ukth = 0xFFFFFFFFu; thr = __int_as_float(0x7F800000);   // keep all
    } else {
        pick_kth<8>(hist1, (uint32_t)kk, part, sel);            // level 1: 11 bits
        if ((uint32_t)kk > sel[2]) {
            ukth = 0u; thr = 0.0f;                              // drop all
        } else {
            const uint32_t p11 = sel[0];
            const uint32_t kA = sel[1];
            __syncthreads();
            pick_kth<4>(csums, kA, part, sel);                  // level 2a: chunk
            const uint32_t chunk = sel[0];
            const uint32_t kB = sel[1];
            __syncthreads();
            pick_kth<8>(h21 + (size_t)chunk * 2048u, kB, part, sel);  // level 2b
            ukth = (p11 << 21) | (chunk << 11) | sel[0];
            thr = neg_loss_precise(unxform(ukth), -1.0f);       // t = -1 exactly
        }
    }

    const float4* x4 = (const float4*)x;
    const float4* t4 = (const float4*)t;
    float4* o4 = (float4*)out;
    const int n4 = n >> 2;
    const int S = gridDim.x * 256;
    int i = blockIdx.x * 256 + threadIdx.x;
    for (; i + 3 * S < n4; i += 4 * S) {
        float4 xa = x4[i], xb = x4[i + S], xc = x4[i + 2 * S], xd = x4[i + 3 * S];
        float4 ta = t4[i], tb = t4[i + S], tc = t4[i + 2 * S], td = t4[i + 3 * S];
        o4[i]         = fin_quad(xa, ta, ukth, thr);
        o4[i + S]     = fin_quad(xb, tb, ukth, thr);
        o4[i + 2 * S] = fin_quad(xc, tc, ukth, thr);
        o4[i + 3 * S] = fin_quad(xd, td, ukth, thr);
    }
    for (; i < n4; i += S) {
        float4 xa = x4[i], ta = t4[i];
        o4[i] = fin_quad(xa, ta, ukth, thr);
    }
    if (blockIdx.x == 0) {
        for (int j = (n4 << 2) + threadIdx.x; j < n; j += 256) {
            out[j] = fin1(x[j], t[j], ukth, thr);
        }
    }
}

extern "C" void kernel_launch(void* const* d_in, const int* in_sizes, int n_in,
                              void* d_out, int out_size, void* d_ws, size_t ws_size,
                              hipStream_t stream) {
    const float* x = (const float*)d_in[0];
    const float* t = (const float*)d_in[1];
    const int* kptr = (const int*)d_in[2];
    float* out = (float*)d_out;
    const int n = in_sizes[0];
    if (n <= 0) return;

    char* ws = (char*)d_ws;
    uint32_t* hist1 = (uint32_t*)(ws + 0);        // 2048 u32
    uint32_t* csums = (uint32_t*)(ws + 8192);     // 1024 u32
    uint32_t* bcnt  = (uint32_t*)(ws + 16384);    // 2048 u32
    uint32_t* h21   = (uint32_t*)(ws + 32768);    // 2^21 u32 (8 MB)
    const size_t h21_end = 32768 + (size_t)(1u << 21) * 4u;

    const int n4 = n >> 2;
    int work = (n4 + 255) / 256;
    if (work < 1) work = 1;
    const int grid = work < 2048 ? work : 2048;

    const int S = grid * 256;
    const uint32_t iters = (uint32_t)(((long long)n4 + 4LL * S - 1) / (4LL * S));
    const uint32_t cap = iters * 4096u + 64u;      // worst case: all negative
    const size_t need = h21_end + (size_t)cap * 4u * (size_t)grid;
    uint32_t* comp = (ws_size >= need) ? (uint32_t*)(ws + h21_end) : nullptr;

    // zero hist1/csums/bcount + h21 (~8.4 MB, one call)
    hipMemsetAsync(d_ws, 0, h21_end, stream);

    k1_hist_compact<<<grid, 256, 0, stream>>>(x, t, comp, bcnt, hist1, cap, n);
    k2_hist21      <<<grid, 256, 0, stream>>>(comp, bcnt, cap, hist1, h21, kptr, x, t, n);
    scanA          <<<1024, 256, 0, stream>>>(h21, csums);
    k_final        <<<grid, 256, 0, stream>>>(x, t, hist1, csums, h21, kptr, out, n);
}